// Round 5
// baseline (268.142 us; speedup 1.0000x reference)
//
#include <hip/hip_runtime.h>
#include <hip/hip_bf16.h>
#include <cstddef>

// Problem constants (from reference)
#define QN 10000
#define DD 64
#define MM 50
#define BB 64
#define TT 512
#define WPAD 52    // padded w row stride in floats (208 B, 16B-aligned rows)
#define CC 32      // chunks (compile-time -> full unroll)
#define LL 16      // steps per chunk = TT/CC
#define MH 25      // m's per half-wave split in kA/kC

__device__ __forceinline__ float rl(float v, int l) {
  return __uint_as_float(__builtin_amdgcn_readlane(__float_as_uint(v), l));
}
__device__ __forceinline__ float sigf(float x) {
  return 1.f / (1.f + __expf(-x));
}
__device__ __forceinline__ float tanhf_fast(float x) {
  const float t2 = __expf(2.f * x);
  return 1.f - 2.f / (t2 + 1.f);
}
__device__ __forceinline__ float f4c(const float4& v, int u) {
  return u == 0 ? v.x : (u == 1 ? v.y : (u == 2 ? v.z : v.w));
}

// ---------------------------------------------------------------------------
// k1: GEMV layout (lane = row). 3 paths by block range, 128 blocks each:
//   path 0: w = softmax(k @ Mk^T)   (Mk^T in LDS, 52-padded rows)
//   path 1: e = sigmoid(v @ e_W + e_b)
//   path 2: a = tanh(v @ a_W + a_b)
// ALL per-thread arrays constant-indexed (full unroll) -> registers, no
// scratch spill. Weights broadcast from LDS (same-address reads, free).
// ---------------------------------------------------------------------------
__global__ __launch_bounds__(256) void k1_gemv(
    const int* __restrict__ question, const int* __restrict__ response,
    const float* __restrict__ k_emb, const float* __restrict__ v_emb,
    const float* __restrict__ Mk,
    const float* __restrict__ e_W, const float* __restrict__ e_b,
    const float* __restrict__ a_W, const float* __restrict__ a_b,
    float* __restrict__ w_buf, float* __restrict__ e_buf, float* __restrict__ a_buf) {
  __shared__ float lds[4160];
  const int tid = (int)threadIdx.x;
  const int lane = tid & 63;
  const int wslot = __builtin_amdgcn_readfirstlane(tid >> 6);
  const int path = blockIdx.x >> 7;          // 0=w, 1=e, 2=a
  const int blk = blockIdx.x & 127;
  const int gid = blk * 4 + wslot;           // 0..511
  const int row = gid * 64 + lane;           // 0..32767

  if (path == 0) {
    const int q = question[row];
    const float* __restrict__ krow = k_emb + (size_t)q * 64;
    // stage Mk^T into LDS: lds[i*52 + m] = Mk[m][i]; pad m=50,51 with 0
    for (int idx = tid; idx < 3328; idx += 256) lds[idx] = 0.f;
    __syncthreads();
    for (int idx = tid; idx < 3200; idx += 256) {
      const int m = idx >> 6, i = idx & 63;
      lds[i * 52 + m] = Mk[idx];
    }
    __syncthreads();

    float l[52];
#pragma unroll
    for (int m = 0; m < 52; ++m) l[m] = 0.f;
#pragma unroll
    for (int i4 = 0; i4 < 16; ++i4) {
      const float4 xv = *(const float4*)(krow + i4 * 4);
#pragma unroll
      for (int u = 0; u < 4; ++u) {
        const float xi = f4c(xv, u);
        const int i = i4 * 4 + u;
#pragma unroll
        for (int j = 0; j < 52; j += 4) {
          const float4 wv = *(const float4*)(&lds[i * 52 + j]);  // broadcast
          l[j]     = fmaf(xi, wv.x, l[j]);
          l[j + 1] = fmaf(xi, wv.y, l[j + 1]);
          l[j + 2] = fmaf(xi, wv.z, l[j + 2]);
          l[j + 3] = fmaf(xi, wv.w, l[j + 3]);
        }
      }
    }
    // per-lane softmax over l[0..49]
    float mx = l[0];
#pragma unroll
    for (int m = 1; m < 50; ++m) mx = fmaxf(mx, l[m]);
    float s = 0.f;
#pragma unroll
    for (int m = 0; m < 50; ++m) { l[m] = __expf(l[m] - mx); s += l[m]; }
    const float inv = 1.f / s;
#pragma unroll
    for (int m = 0; m < 50; ++m) l[m] *= inv;
    l[50] = 0.f; l[51] = 0.f;
    float* __restrict__ wo = w_buf + (size_t)row * WPAD;
#pragma unroll
    for (int m = 0; m < 52; m += 4) {
      float4 o; o.x = l[m]; o.y = l[m + 1]; o.z = l[m + 2]; o.w = l[m + 3];
      *(float4*)(wo + m) = o;
    }
  } else {
    const int q = question[row];
    const int r = response[row];
    const float* __restrict__ vrow = v_emb + ((size_t)q + (size_t)QN * r) * 64;
    const float* __restrict__ W = (path == 1) ? e_W : a_W;
    const float* __restrict__ Bv = (path == 1) ? e_b : a_b;
    for (int idx = tid; idx < 4096; idx += 256) lds[idx] = W[idx];
    if (tid < 64) lds[4096 + tid] = Bv[tid];
    __syncthreads();

    float x[64];
#pragma unroll
    for (int i = 0; i < 64; i += 4) {
      const float4 t = *(const float4*)(vrow + i);
      x[i] = t.x; x[i + 1] = t.y; x[i + 2] = t.z; x[i + 3] = t.w;
    }
    float* __restrict__ o = ((path == 1) ? e_buf : a_buf) + (size_t)row * 64;
#pragma unroll
    for (int half = 0; half < 2; ++half) {
      float acc[32];
#pragma unroll
      for (int j = 0; j < 32; ++j) acc[j] = 0.f;
#pragma unroll
      for (int i = 0; i < 64; ++i) {
#pragma unroll
        for (int j = 0; j < 32; j += 4) {
          const float4 wv = *(const float4*)(&lds[i * 64 + half * 32 + j]);
          acc[j]     = fmaf(x[i], wv.x, acc[j]);
          acc[j + 1] = fmaf(x[i], wv.y, acc[j + 1]);
          acc[j + 2] = fmaf(x[i], wv.z, acc[j + 2]);
          acc[j + 3] = fmaf(x[i], wv.w, acc[j + 3]);
        }
      }
      if (path == 1) {
#pragma unroll
        for (int j = 0; j < 32; j += 4) {
          float4 ov;
          ov.x = sigf(acc[j]     + lds[4096 + half * 32 + j]);
          ov.y = sigf(acc[j + 1] + lds[4096 + half * 32 + j + 1]);
          ov.z = sigf(acc[j + 2] + lds[4096 + half * 32 + j + 2]);
          ov.w = sigf(acc[j + 3] + lds[4096 + half * 32 + j + 3]);
          *(float4*)(o + half * 32 + j) = ov;
        }
      } else {
#pragma unroll
        for (int j = 0; j < 32; j += 4) {
          float4 ov;
          ov.x = tanhf_fast(acc[j]     + lds[4096 + half * 32 + j]);
          ov.y = tanhf_fast(acc[j + 1] + lds[4096 + half * 32 + j + 1]);
          ov.z = tanhf_fast(acc[j + 2] + lds[4096 + half * 32 + j + 2]);
          ov.w = tanhf_fast(acc[j + 3] + lds[4096 + half * 32 + j + 3]);
          *(float4*)(o + half * 32 + j) = ov;
        }
      }
    }
  }
}

// ---------------------------------------------------------------------------
// kA: composed affine (A,B) per (m,d) for each (b,chunk). Two waves per unit
// (25 m's each); lane = d; fully unrolled; no barriers, no LDS. (unchanged)
// ---------------------------------------------------------------------------
__global__ __launch_bounds__(256) void kA_chunk(
    const float* __restrict__ w_buf, const float* __restrict__ e_buf,
    const float* __restrict__ a_buf, const float* __restrict__ mask,
    float* __restrict__ A_arr, float* __restrict__ B_arr) {
  const int lane = threadIdx.x & 63;
  const int wslot = __builtin_amdgcn_readfirstlane((int)(threadIdx.x >> 6));
  const int gid = blockIdx.x * 4 + wslot;              // 0..4095
  const int unit = gid >> 1;                           // b*CC + c
  const int m0 = (gid & 1) * MH;
  const int b = unit >> 5;                             // CC = 32
  const int c = unit & 31;

  float Am[MH], Bm[MH];
#pragma unroll
  for (int m = 0; m < MH; ++m) { Am[m] = 1.f; Bm[m] = 0.f; }

  const size_t row0 = (size_t)b * TT + c * LL;
#pragma unroll
  for (int j = 0; j < LL; ++j) {
    const size_t row = row0 + j;
    const float wv = w_buf[row * WPAD + lane];         // coalesced lane load
    const float ed = e_buf[row * 64 + lane];
    const float ad = a_buf[row * 64 + lane];
    const float mv = mask[row];
    if (mv == 1.0f) {
#pragma unroll
      for (int m = 0; m < MH; ++m) {
        const float wm = rl(wv, m0 + m);               // wave-uniform scalar
        const float al = fmaf(-wm, ed, 1.0f);
        Am[m] *= al;
        Bm[m] = fmaf(Bm[m], al, wm * ad);
      }
    }
  }
  float* __restrict__ Ad = A_arr + (size_t)unit * (MM * 64);
  float* __restrict__ Bd = B_arr + (size_t)unit * (MM * 64);
#pragma unroll
  for (int m = 0; m < MH; ++m) {
    Ad[(m0 + m) * 64 + lane] = Am[m];
    Bd[(m0 + m) * 64 + lane] = Bm[m];
  }
}

// ---------------------------------------------------------------------------
// kB: chunk-entry states. Parallel over B*M*D = 204,800 elements. (unchanged)
// ---------------------------------------------------------------------------
__global__ __launch_bounds__(256) void kB_entry(
    const float* __restrict__ A_arr, const float* __restrict__ B_arr,
    const float* __restrict__ Mv0, float* __restrict__ entry) {
  const int idx = blockIdx.x * 256 + (int)threadIdx.x; // < 204800
  const int b = idx / (MM * 64);
  const int r = idx - b * (MM * 64);
  const size_t base = (size_t)b * CC * (MM * 64) + r;

  float Ac[CC], Bc[CC];
#pragma unroll
  for (int c = 0; c < CC; ++c) {
    Ac[c] = A_arr[base + (size_t)c * (MM * 64)];
    Bc[c] = B_arr[base + (size_t)c * (MM * 64)];
  }
  float s = Mv0[r];
#pragma unroll
  for (int c = 0; c < CC; ++c) {
    entry[base + (size_t)c * (MM * 64)] = s;
    s = fmaf(Ac[c], s, Bc[c]);
  }
}

// ---------------------------------------------------------------------------
// kC: replay each chunk from its entry state, emitting partial reads.
// Two waves per unit; fully unrolled; no barriers. (unchanged)
// ---------------------------------------------------------------------------
__global__ __launch_bounds__(256) void kC_read(
    const float* __restrict__ w_buf, const float* __restrict__ e_buf,
    const float* __restrict__ a_buf, const float* __restrict__ mask,
    const float* __restrict__ entry, float* __restrict__ read_part,
    size_t rN) {
  const int lane = threadIdx.x & 63;
  const int wslot = __builtin_amdgcn_readfirstlane((int)(threadIdx.x >> 6));
  const int gid = blockIdx.x * 4 + wslot;              // 0..4095
  const int unit = gid >> 1;                           // b*CC + c
  const int half = gid & 1;
  const int m0 = half * MH;
  const int b = unit >> 5;
  const int c = unit & 31;

  float s[MH];
  const float* __restrict__ ep = entry + (size_t)unit * (MM * 64);
#pragma unroll
  for (int m = 0; m < MH; ++m) s[m] = ep[(m0 + m) * 64 + lane];

  float* __restrict__ rp = read_part + half * rN;
#pragma unroll
  for (int j = 0; j < LL; ++j) {
    const int t = c * LL + j;
    const size_t row = (size_t)b * TT + t;
    const float wv = w_buf[row * WPAD + lane];
    const float ed = e_buf[row * 64 + lane];
    const float ad = a_buf[row * 64 + lane];
    const float mv = mask[row];

    if (t >= 1) {                                      // uniform branch
      float a0 = 0.f, a1 = 0.f;
#pragma unroll
      for (int m = 0; m < MH; m += 2) {
        a0 = fmaf(rl(wv, m0 + m), s[m], a0);
        if (m + 1 < MH) a1 = fmaf(rl(wv, m0 + m + 1), s[m + 1], a1);
      }
      rp[((size_t)b * (TT - 1) + (t - 1)) * 64 + lane] = a0 + a1;
    }
    if (mv == 1.0f) {
#pragma unroll
      for (int m = 0; m < MH; ++m) {
        const float wm = rl(wv, m0 + m);
        s[m] = fmaf(wm, fmaf(-s[m], ed, ad), s[m]);
      }
    }
  }
}

// ---------------------------------------------------------------------------
// k3: GEMV layout (lane = row). f = tanh([read | k_{t+1}] @ f_W + f_b);
// p = f @ p_W + p_b. f_W in LDS (broadcast reads); output d computed in two
// 32-wide tiles (f[32] regs); one reusable x[64]; no scratch, no cross-lane.
// ---------------------------------------------------------------------------
__global__ __launch_bounds__(256) void k3_gemv(
    const int* __restrict__ question, const float* __restrict__ k_emb,
    const float* __restrict__ read_part, size_t rN,
    const float* __restrict__ f_W, const float* __restrict__ f_b,
    const float* __restrict__ p_W, const float* __restrict__ p_b,
    float* __restrict__ out) {
  __shared__ float lds[8192 + 128];
  const int tid = (int)threadIdx.x;
  const int lane = tid & 63;
  const int wslot = __builtin_amdgcn_readfirstlane(tid >> 6);
  const int gid = blockIdx.x * 4 + wslot;              // 0..511

  for (int idx = tid; idx < 8192; idx += 256) lds[idx] = f_W[idx];
  if (tid < 64) lds[8192 + tid] = f_b[tid];
  else if (tid < 128) lds[8192 + tid] = p_W[tid - 64];
  __syncthreads();
  if (gid >= 511) return;                              // after the barrier

  const int row = gid * 64 + lane;                     // 0..32703
  const int b = row / (TT - 1);
  const int tp = row - b * (TT - 1);
  const int qn = question[b * TT + tp + 1];
  const float* __restrict__ r0 = read_part + (size_t)row * 64;
  const float* __restrict__ r1 = r0 + rN;
  const float* __restrict__ krow = k_emb + (size_t)qn * 64;

  float p = 0.f;
#pragma unroll
  for (int tile = 0; tile < 2; ++tile) {
    float f[32];
#pragma unroll
    for (int j = 0; j < 32; ++j) f[j] = 0.f;

    float x[64];
    // input half 0: read = r0 + r1
#pragma unroll
    for (int i = 0; i < 64; i += 4) {
      const float4 u = *(const float4*)(r0 + i);
      const float4 v = *(const float4*)(r1 + i);
      x[i] = u.x + v.x; x[i + 1] = u.y + v.y;
      x[i + 2] = u.z + v.z; x[i + 3] = u.w + v.w;
    }
#pragma unroll
    for (int i = 0; i < 64; ++i) {
#pragma unroll
      for (int j = 0; j < 32; j += 4) {
        const float4 wv = *(const float4*)(&lds[i * 64 + tile * 32 + j]);
        f[j]     = fmaf(x[i], wv.x, f[j]);
        f[j + 1] = fmaf(x[i], wv.y, f[j + 1]);
        f[j + 2] = fmaf(x[i], wv.z, f[j + 2]);
        f[j + 3] = fmaf(x[i], wv.w, f[j + 3]);
      }
    }
    // input half 1: k_{t+1}
#pragma unroll
    for (int i = 0; i < 64; i += 4) {
      const float4 t = *(const float4*)(krow + i);
      x[i] = t.x; x[i + 1] = t.y; x[i + 2] = t.z; x[i + 3] = t.w;
    }
#pragma unroll
    for (int i = 0; i < 64; ++i) {
#pragma unroll
      for (int j = 0; j < 32; j += 4) {
        const float4 wv = *(const float4*)(&lds[(64 + i) * 64 + tile * 32 + j]);
        f[j]     = fmaf(x[i], wv.x, f[j]);
        f[j + 1] = fmaf(x[i], wv.y, f[j + 1]);
        f[j + 2] = fmaf(x[i], wv.z, f[j + 2]);
        f[j + 3] = fmaf(x[i], wv.w, f[j + 3]);
      }
    }
    // epilogue for this tile
#pragma unroll
    for (int j = 0; j < 32; ++j) {
      const float fv = tanhf_fast(f[j] + lds[8192 + tile * 32 + j]);
      p = fmaf(fv, lds[8256 + tile * 32 + j], p);
    }
  }
  out[row] = p + p_b[0];
}

// ---------------------------------------------------------------------------
extern "C" void kernel_launch(void* const* d_in, const int* in_sizes, int n_in,
                              void* d_out, int out_size, void* d_ws, size_t ws_size,
                              hipStream_t stream) {
  const int*   question = (const int*)d_in[0];
  const int*   response = (const int*)d_in[1];
  const float* mask     = (const float*)d_in[2];
  const float* k_emb    = (const float*)d_in[3];
  const float* v_emb    = (const float*)d_in[4];
  const float* Mk       = (const float*)d_in[5];
  const float* Mv0      = (const float*)d_in[6];
  const float* e_W      = (const float*)d_in[7];
  const float* e_b      = (const float*)d_in[8];
  const float* a_W      = (const float*)d_in[9];
  const float* a_b      = (const float*)d_in[10];
  const float* f_W      = (const float*)d_in[11];
  const float* f_b      = (const float*)d_in[12];
  const float* p_W      = (const float*)d_in[13];
  const float* p_b      = (const float*)d_in[14];
  float* out = (float*)d_out;

  // workspace layout (floats)
  const size_t wN = (size_t)BB * TT * WPAD;       // 1,703,936
  const size_t eN = (size_t)BB * TT * 64;         // 2,097,152
  const size_t rN = (size_t)BB * (TT - 1) * 64;   // 2,093,056
  const size_t abN = (size_t)BB * CC * MM * 64;   // 6,553,600
  float* ws = (float*)d_ws;
  float* w_buf     = ws;
  float* e_buf     = w_buf + wN;
  float* a_buf     = e_buf + eN;
  float* read_part = a_buf + eN;                  // 2 * rN
  float* A_arr     = read_part + 2 * rN;
  float* B_arr     = A_arr + abN;
  float* entry     = B_arr + abN;
  // total = 29,745,152 floats = 119 MB (< ws_size)

  hipLaunchKernelGGL(k1_gemv, dim3(384), dim3(256), 0, stream,
                     question, response, k_emb, v_emb, Mk, e_W, e_b, a_W, a_b,
                     w_buf, e_buf, a_buf);
  hipLaunchKernelGGL(kA_chunk, dim3(1024), dim3(256), 0, stream,
                     w_buf, e_buf, a_buf, mask, A_arr, B_arr);
  hipLaunchKernelGGL(kB_entry, dim3((BB * MM * 64) / 256), dim3(256), 0, stream,
                     A_arr, B_arr, Mv0, entry);
  hipLaunchKernelGGL(kC_read, dim3(1024), dim3(256), 0, stream,
                     w_buf, e_buf, a_buf, mask, entry, read_part, rN);
  hipLaunchKernelGGL(k3_gemv, dim3(128), dim3(256), 0, stream,
                     question, k_emb, read_part, rN, f_W, f_b, p_W, p_b, out);
}

// Round 6
// 241.952 us; speedup vs baseline: 1.1082x; 1.1082x over previous
//
#include <hip/hip_runtime.h>
#include <hip/hip_bf16.h>
#include <cstddef>

// Problem constants (from reference)
#define QN 10000
#define DD 64
#define MM 50
#define BB 64
#define TT 512
#define WPAD 52    // padded w row stride in floats (208 B = 13*16, 16B-aligned)
#define CC 16      // chunks (compile-time)
#define LL 32      // steps per chunk = TT/CC

__device__ __forceinline__ float sigf(float x) {
  return 1.f / (1.f + __expf(-x));
}
__device__ __forceinline__ float tanhf_fast(float x) {
  const float t2 = __expf(2.f * x);
  return 1.f - 2.f / (t2 + 1.f);
}
__device__ __forceinline__ float f4c(const float4& v, int u) {
  return u == 0 ? v.x : (u == 1 ? v.y : (u == 2 ? v.z : v.w));
}

// ---------------------------------------------------------------------------
// k0: transpose Mk [50][64] -> MkT [64][52] (rows 52-padded) so k1's w-path
// can stream weight rows with contiguous scalar loads.
// ---------------------------------------------------------------------------
__global__ __launch_bounds__(64) void k0_mkT(
    const float* __restrict__ Mk, float* __restrict__ MkT) {
  for (int idx = (int)threadIdx.x; idx < MM * 64; idx += 64) {
    const int m = idx >> 6, i = idx & 63;
    MkT[i * WPAD + m] = Mk[idx];
  }
}

// ---------------------------------------------------------------------------
// k1 (fused, SGPR-streamed weights, no LDS): 64-thread blocks, lane = row.
//   blocks [0,512):    w = softmax(k @ Mk^T)    (MkT rows via s_load)
//   blocks [512,1024): e = sigmoid(v@e_W+e_b); a = tanh(v@a_W+a_b)
// x streamed as float4 chunks (no big per-lane arrays -> no scratch spill).
// ---------------------------------------------------------------------------
__global__ __launch_bounds__(64) void k1_gemv(
    const int* __restrict__ question, const int* __restrict__ response,
    const float* __restrict__ k_emb, const float* __restrict__ v_emb,
    const float* __restrict__ MkT,
    const float* __restrict__ e_W, const float* __restrict__ e_b,
    const float* __restrict__ a_W, const float* __restrict__ a_b,
    float* __restrict__ w_buf, float* __restrict__ e_buf, float* __restrict__ a_buf) {
  const int lane = (int)threadIdx.x;
  const int blk = (int)blockIdx.x;

  if (blk < 512) {
    const int row = blk * 64 + lane;
    const int q = question[row];
    const float* __restrict__ krow = k_emb + (size_t)q * 64;
    float l[52];
#pragma unroll
    for (int m = 0; m < 52; ++m) l[m] = 0.f;
#pragma unroll 2
    for (int i4 = 0; i4 < 16; ++i4) {
      const float4 xv = *(const float4*)(krow + i4 * 4);
#pragma unroll
      for (int u = 0; u < 4; ++u) {
        const float xi = f4c(xv, u);
        const float* __restrict__ wr = MkT + (i4 * 4 + u) * WPAD;  // uniform
#pragma unroll
        for (int m = 0; m < 50; ++m) l[m] = fmaf(xi, wr[m], l[m]);
      }
    }
    float mx = l[0];
#pragma unroll
    for (int m = 1; m < 50; ++m) mx = fmaxf(mx, l[m]);
    float s = 0.f;
#pragma unroll
    for (int m = 0; m < 50; ++m) { l[m] = __expf(l[m] - mx); s += l[m]; }
    const float inv = 1.f / s;
#pragma unroll
    for (int m = 0; m < 50; ++m) l[m] *= inv;
    l[50] = 0.f; l[51] = 0.f;
    float* __restrict__ wo = w_buf + (size_t)row * WPAD;
#pragma unroll
    for (int m = 0; m < 52; m += 4) {
      float4 o; o.x = l[m]; o.y = l[m + 1]; o.z = l[m + 2]; o.w = l[m + 3];
      *(float4*)(wo + m) = o;
    }
  } else {
    const int row = (blk - 512) * 64 + lane;
    const int q = question[row];
    const int r = response[row];
    const float* __restrict__ vrow = v_emb + ((size_t)q + (size_t)QN * r) * 64;

    float acc[64];
    // ---- e pass ----
#pragma unroll
    for (int d = 0; d < 64; ++d) acc[d] = 0.f;
#pragma unroll 2
    for (int i4 = 0; i4 < 16; ++i4) {
      const float4 xv = *(const float4*)(vrow + i4 * 4);
#pragma unroll
      for (int u = 0; u < 4; ++u) {
        const float xi = f4c(xv, u);
        const float* __restrict__ wr = e_W + (i4 * 4 + u) * 64;   // uniform
#pragma unroll
        for (int d = 0; d < 64; ++d) acc[d] = fmaf(xi, wr[d], acc[d]);
      }
    }
    {
      float* __restrict__ o = e_buf + (size_t)row * 64;
#pragma unroll
      for (int d = 0; d < 64; d += 4) {
        float4 ov;
        ov.x = sigf(acc[d] + e_b[d]);
        ov.y = sigf(acc[d + 1] + e_b[d + 1]);
        ov.z = sigf(acc[d + 2] + e_b[d + 2]);
        ov.w = sigf(acc[d + 3] + e_b[d + 3]);
        *(float4*)(o + d) = ov;
      }
    }
    // ---- a pass ----
#pragma unroll
    for (int d = 0; d < 64; ++d) acc[d] = 0.f;
#pragma unroll 2
    for (int i4 = 0; i4 < 16; ++i4) {
      const float4 xv = *(const float4*)(vrow + i4 * 4);
#pragma unroll
      for (int u = 0; u < 4; ++u) {
        const float xi = f4c(xv, u);
        const float* __restrict__ wr = a_W + (i4 * 4 + u) * 64;   // uniform
#pragma unroll
        for (int d = 0; d < 64; ++d) acc[d] = fmaf(xi, wr[d], acc[d]);
      }
    }
    {
      float* __restrict__ o = a_buf + (size_t)row * 64;
#pragma unroll
      for (int d = 0; d < 64; d += 4) {
        float4 ov;
        ov.x = tanhf_fast(acc[d] + a_b[d]);
        ov.y = tanhf_fast(acc[d + 1] + a_b[d + 1]);
        ov.z = tanhf_fast(acc[d + 2] + a_b[d + 2]);
        ov.w = tanhf_fast(acc[d + 3] + a_b[d + 3]);
        *(float4*)(o + d) = ov;
      }
    }
  }
}

// ---------------------------------------------------------------------------
// kA: composed affine (A,B) per (m,d) for each (b,chunk). ONE wave per unit,
// all 50 m's in registers; lane = d; w row + mask via uniform scalar loads.
// ---------------------------------------------------------------------------
__global__ __launch_bounds__(64) void kA_chunk(
    const float* __restrict__ w_buf, const float* __restrict__ e_buf,
    const float* __restrict__ a_buf, const float* __restrict__ mask,
    float* __restrict__ A_arr, float* __restrict__ B_arr) {
  const int lane = (int)threadIdx.x;
  const int unit = (int)blockIdx.x;                    // b*CC + c
  const int b = unit >> 4;
  const int c = unit & (CC - 1);

  float Am[MM], Bm[MM];
#pragma unroll
  for (int m = 0; m < MM; ++m) { Am[m] = 1.f; Bm[m] = 0.f; }

  const size_t row0 = (size_t)b * TT + c * LL;
#pragma unroll 2
  for (int j = 0; j < LL; ++j) {
    const size_t row = row0 + j;
    const float ed = e_buf[row * 64 + lane];
    const float ad = a_buf[row * 64 + lane];
    const float mv = mask[row];                        // uniform
    const float* __restrict__ wr = w_buf + row * WPAD; // uniform -> s_load
    if (mv == 1.0f) {
#pragma unroll
      for (int m = 0; m < MM; ++m) {
        const float wm = wr[m];
        const float al = fmaf(-wm, ed, 1.0f);
        Am[m] *= al;
        Bm[m] = fmaf(Bm[m], al, wm * ad);
      }
    }
  }
  float* __restrict__ Ad = A_arr + (size_t)unit * (MM * 64);
  float* __restrict__ Bd = B_arr + (size_t)unit * (MM * 64);
#pragma unroll
  for (int m = 0; m < MM; ++m) {
    Ad[m * 64 + lane] = Am[m];
    Bd[m * 64 + lane] = Bm[m];
  }
}

// ---------------------------------------------------------------------------
// kB: chunk-entry states. Parallel over B*M*D = 204,800 elements; CC=16
// chain fully unrolled, all loads issued up front.
// ---------------------------------------------------------------------------
__global__ __launch_bounds__(256) void kB_entry(
    const float* __restrict__ A_arr, const float* __restrict__ B_arr,
    const float* __restrict__ Mv0, float* __restrict__ entry) {
  const int idx = blockIdx.x * 256 + (int)threadIdx.x; // < 204800
  const int b = idx / (MM * 64);
  const int r = idx - b * (MM * 64);
  const size_t base = (size_t)b * CC * (MM * 64) + r;

  float Ac[CC], Bc[CC];
#pragma unroll
  for (int c = 0; c < CC; ++c) {
    Ac[c] = A_arr[base + (size_t)c * (MM * 64)];
    Bc[c] = B_arr[base + (size_t)c * (MM * 64)];
  }
  float s = Mv0[r];
#pragma unroll
  for (int c = 0; c < CC; ++c) {
    entry[base + (size_t)c * (MM * 64)] = s;
    s = fmaf(Ac[c], s, Bc[c]);
  }
}

// ---------------------------------------------------------------------------
// kC: replay each chunk from its entry state, emitting full reads.
// ONE wave per unit, all 50 m's in registers; w via uniform scalar loads.
// ---------------------------------------------------------------------------
__global__ __launch_bounds__(64) void kC_read(
    const float* __restrict__ w_buf, const float* __restrict__ e_buf,
    const float* __restrict__ a_buf, const float* __restrict__ mask,
    const float* __restrict__ entry, float* __restrict__ read_buf) {
  const int lane = (int)threadIdx.x;
  const int unit = (int)blockIdx.x;                    // b*CC + c
  const int b = unit >> 4;
  const int c = unit & (CC - 1);

  float s[MM];
  const float* __restrict__ ep = entry + (size_t)unit * (MM * 64);
#pragma unroll
  for (int m = 0; m < MM; ++m) s[m] = ep[m * 64 + lane];

#pragma unroll 2
  for (int j = 0; j < LL; ++j) {
    const int t = c * LL + j;
    const size_t row = (size_t)b * TT + t;
    const float ed = e_buf[row * 64 + lane];
    const float ad = a_buf[row * 64 + lane];
    const float mv = mask[row];                        // uniform
    const float* __restrict__ wr = w_buf + row * WPAD; // uniform -> s_load

    if (t >= 1) {                                      // uniform branch
      float a0 = 0.f, a1 = 0.f;
#pragma unroll
      for (int m = 0; m < MM; m += 2) {
        a0 = fmaf(wr[m], s[m], a0);
        a1 = fmaf(wr[m + 1], s[m + 1], a1);
      }
      read_buf[((size_t)b * (TT - 1) + (t - 1)) * 64 + lane] = a0 + a1;
    }
    if (mv == 1.0f) {
#pragma unroll
      for (int m = 0; m < MM; ++m)
        s[m] = fmaf(wr[m], fmaf(-s[m], ed, ad), s[m]);
    }
  }
}

// ---------------------------------------------------------------------------
// k3: f = tanh([read | k_{t+1}] @ f_W + f_b); p = f @ p_W + p_b.
// Lane = row; f_W rows streamed via uniform scalar loads; f[64] in regs.
// ---------------------------------------------------------------------------
__global__ __launch_bounds__(64) void k3_out(
    const int* __restrict__ question, const float* __restrict__ k_emb,
    const float* __restrict__ read_buf,
    const float* __restrict__ f_W, const float* __restrict__ f_b,
    const float* __restrict__ p_W, const float* __restrict__ p_b,
    float* __restrict__ out) {
  const int lane = (int)threadIdx.x;
  const int row = (int)blockIdx.x * 64 + lane;         // 0..32703 (511 blocks)
  const int b = row / (TT - 1);
  const int tp = row - b * (TT - 1);
  const int qn = question[b * TT + tp + 1];
  const float* __restrict__ rrow = read_buf + (size_t)row * 64;
  const float* __restrict__ krow = k_emb + (size_t)qn * 64;

  float f[64];
#pragma unroll
  for (int d = 0; d < 64; ++d) f[d] = 0.f;
#pragma unroll 2
  for (int i4 = 0; i4 < 16; ++i4) {
    const float4 xv = *(const float4*)(rrow + i4 * 4);
#pragma unroll
    for (int u = 0; u < 4; ++u) {
      const float xi = f4c(xv, u);
      const float* __restrict__ wr = f_W + (i4 * 4 + u) * 64;     // uniform
#pragma unroll
      for (int d = 0; d < 64; ++d) f[d] = fmaf(xi, wr[d], f[d]);
    }
  }
#pragma unroll 2
  for (int i4 = 0; i4 < 16; ++i4) {
    const float4 xv = *(const float4*)(krow + i4 * 4);
#pragma unroll
    for (int u = 0; u < 4; ++u) {
      const float xi = f4c(xv, u);
      const float* __restrict__ wr = f_W + (64 + i4 * 4 + u) * 64; // uniform
#pragma unroll
      for (int d = 0; d < 64; ++d) f[d] = fmaf(xi, wr[d], f[d]);
    }
  }
  float p = 0.f;
#pragma unroll
  for (int d = 0; d < 64; ++d) {
    const float fv = tanhf_fast(f[d] + f_b[d]);        // f_b,p_W uniform
    p = fmaf(fv, p_W[d], p);
  }
  out[row] = p + p_b[0];
}

// ---------------------------------------------------------------------------
extern "C" void kernel_launch(void* const* d_in, const int* in_sizes, int n_in,
                              void* d_out, int out_size, void* d_ws, size_t ws_size,
                              hipStream_t stream) {
  const int*   question = (const int*)d_in[0];
  const int*   response = (const int*)d_in[1];
  const float* mask     = (const float*)d_in[2];
  const float* k_emb    = (const float*)d_in[3];
  const float* v_emb    = (const float*)d_in[4];
  const float* Mk       = (const float*)d_in[5];
  const float* Mv0      = (const float*)d_in[6];
  const float* e_W      = (const float*)d_in[7];
  const float* e_b      = (const float*)d_in[8];
  const float* a_W      = (const float*)d_in[9];
  const float* a_b      = (const float*)d_in[10];
  const float* f_W      = (const float*)d_in[11];
  const float* f_b      = (const float*)d_in[12];
  const float* p_W      = (const float*)d_in[13];
  const float* p_b      = (const float*)d_in[14];
  float* out = (float*)d_out;

  // workspace layout (floats)
  const size_t wN  = (size_t)BB * TT * WPAD;       // 1,703,936
  const size_t eN  = (size_t)BB * TT * 64;         // 2,097,152
  const size_t rN  = (size_t)BB * (TT - 1) * 64;   // 2,093,056
  const size_t abN = (size_t)BB * CC * MM * 64;    // 3,276,800
  float* ws = (float*)d_ws;
  float* MkT      = ws;                            // 64*52 = 3,328
  float* w_buf    = MkT + 64 * WPAD;
  float* e_buf    = w_buf + wN;
  float* a_buf    = e_buf + eN;
  float* read_buf = a_buf + eN;
  float* A_arr    = read_buf + rN;
  float* B_arr    = A_arr + abN;
  float* entry    = B_arr + abN;
  // total ~ 17.8M floats = 71 MB (< ws_size)

  hipLaunchKernelGGL(k0_mkT, dim3(1), dim3(64), 0, stream, Mk, MkT);
  hipLaunchKernelGGL(k1_gemv, dim3(1024), dim3(64), 0, stream,
                     question, response, k_emb, v_emb, MkT, e_W, e_b, a_W, a_b,
                     w_buf, e_buf, a_buf);
  hipLaunchKernelGGL(kA_chunk, dim3(BB * CC), dim3(64), 0, stream,
                     w_buf, e_buf, a_buf, mask, A_arr, B_arr);
  hipLaunchKernelGGL(kB_entry, dim3((BB * MM * 64) / 256), dim3(256), 0, stream,
                     A_arr, B_arr, Mv0, entry);
  hipLaunchKernelGGL(kC_read, dim3(BB * CC), dim3(64), 0, stream,
                     w_buf, e_buf, a_buf, mask, entry, read_buf);
  hipLaunchKernelGGL(k3_out, dim3(511), dim3(64), 0, stream,
                     question, k_emb, read_buf, f_W, f_b, p_W, p_b, out);
}